// Round 1
// baseline (409.812 us; speedup 1.0000x reference)
//
#include <hip/hip_runtime.h>
#include <stdint.h>

#define GSZ 256
#define NV (GSZ*GSZ)
#define NS 2048

struct F3 { float x, y, z; };

__device__ __forceinline__ F3 ldv3(const float* __restrict__ p, int idx) {
    const float* q = p + 3*(size_t)idx;
    F3 r; r.x = q[0]; r.y = q[1]; r.z = q[2]; return r;
}
__device__ __forceinline__ F3 f3sub(F3 a, F3 b) { return F3{a.x-b.x, a.y-b.y, a.z-b.z}; }
__device__ __forceinline__ F3 f3cross(F3 a, F3 b) {
    return F3{a.y*b.z - a.z*b.y, a.z*b.x - a.x*b.z, a.x*b.y - a.y*b.x};
}
__device__ __forceinline__ float f3dot(F3 a, F3 b) { return a.x*b.x + a.y*b.y + a.z*b.z; }

__device__ __forceinline__ uint64_t splitmix64(uint64_t& s) {
    s += 0x9E3779B97F4A7C15ULL;
    uint64_t z = s;
    z = (z ^ (z >> 30)) * 0xBF58476D1CE4E5B9ULL;
    z = (z ^ (z >> 27)) * 0x94D049BB133111EBULL;
    return z ^ (z >> 31);
}

// valid result on thread 0 only; blockDim.x == 256
__device__ __forceinline__ float blockReduceSum256(float v) {
    __shared__ float s[4];
    int lane = threadIdx.x & 63, w = threadIdx.x >> 6;
    #pragma unroll
    for (int o = 32; o > 0; o >>= 1) v += __shfl_down(v, o, 64);
    if (lane == 0) s[w] = v;
    __syncthreads();
    if (threadIdx.x == 0) v = s[0] + s[1] + s[2] + s[3];
    return v;
}

__global__ void k_init(double* acc, unsigned int* maxAreaU, unsigned int* minarr, int n) {
    int gid = blockIdx.x*256 + threadIdx.x;
    if (gid < n) minarr[gid] = 0xFFFFFFFFu;
    if (gid < 5) acc[gid] = 0.0;
    if (gid == 5) *maxAreaU = 0u;
}

// max face area over both clouds, all meshes (for rejection sampling)
__global__ void k_maxarea(const float* __restrict__ vp, const float* __restrict__ vt,
                          const int* __restrict__ faces, int B, int F,
                          unsigned int* maxAreaU) {
    int total = 2*B*F;
    float m = 0.f;
    for (int gid = blockIdx.x*blockDim.x + threadIdx.x; gid < total;
         gid += gridDim.x*blockDim.x) {
        int cloud = gid >= B*F;
        int rem = cloud ? gid - B*F : gid;
        int b = rem / F, f = rem - b*F;
        const float* verts = (cloud ? vt : vp) + (size_t)b*NV*3;
        int i0 = faces[3*f], i1 = faces[3*f+1], i2 = faces[3*f+2];
        F3 v0 = ldv3(verts, i0), v1 = ldv3(verts, i1), v2 = ldv3(verts, i2);
        F3 c = f3cross(f3sub(v1, v0), f3sub(v2, v0));
        float area = 0.5f * sqrtf(f3dot(c, c));
        m = fmaxf(m, area);
    }
    #pragma unroll
    for (int o = 32; o > 0; o >>= 1) m = fmaxf(m, __shfl_down(m, o, 64));
    __shared__ float s[4];
    int lane = threadIdx.x & 63, w = threadIdx.x >> 6;
    if (lane == 0) s[w] = m;
    __syncthreads();
    if (threadIdx.x == 0) {
        m = fmaxf(fmaxf(s[0], s[1]), fmaxf(s[2], s[3]));
        atomicMax(maxAreaU, __float_as_uint(m));
    }
}

// area-weighted surface sampling via rejection; samples[cloud][b][i][3]
__global__ void k_sample(const float* __restrict__ vp, const float* __restrict__ vt,
                         const int* __restrict__ faces, int B, int F,
                         const unsigned int* __restrict__ maxAreaU,
                         float* __restrict__ samples) {
    int gid = blockIdx.x*256 + threadIdx.x;   // 2*B*NS threads exact
    int cloud = gid / (B*NS);
    int rem = gid - cloud*(B*NS);
    int b = rem / NS;
    const float* verts = (cloud ? vt : vp) + (size_t)b*NV*3;
    float maxA = __uint_as_float(*maxAreaU);

    uint64_t st = ((uint64_t)(gid + 1) * 0x9E3779B97F4A7C15ULL) ^ 0xC0FFEE123456789ULL;
    F3 v0{}, v1{}, v2{};
    for (int it = 0; it < 256; ++it) {
        uint64_t r = splitmix64(st);
        uint32_t r1 = (uint32_t)r, r2 = (uint32_t)(r >> 32);
        int f = (int)(((uint64_t)r1 * (uint32_t)F) >> 32);   // Lemire range map
        int i0 = faces[3*f], i1 = faces[3*f+1], i2 = faces[3*f+2];
        v0 = ldv3(verts, i0); v1 = ldv3(verts, i1); v2 = ldv3(verts, i2);
        F3 c = f3cross(f3sub(v1, v0), f3sub(v2, v0));
        float area = 0.5f * sqrtf(f3dot(c, c));
        float u = (r2 >> 8) * (1.f/16777216.f);
        if (u * maxA <= area) break;                         // accept prob = area/maxA
    }
    uint64_t r = splitmix64(st);
    float u0 = ((uint32_t)r >> 8) * (1.f/16777216.f);
    float u1 = ((uint32_t)(r >> 32) >> 8) * (1.f/16777216.f);
    float su = sqrtf(u0);
    float w0 = 1.f - su, w1 = su * (1.f - u1), w2 = su * u1;
    float* o = samples + (size_t)rem*3 + (size_t)cloud*B*NS*3;
    o[0] = w0*v0.x + w1*v1.x + w2*v2.x;
    o[1] = w0*v0.y + w1*v1.y + w2*v2.y;
    o[2] = w0*v0.z + w1*v1.z + w2*v2.z;
}

// grid: (NS/256, B, 4); z = dir*2 + dstHalf. Per-thread min over 1024 dst pts.
__global__ void k_chamfer(const float* __restrict__ samples, int B,
                          unsigned int* __restrict__ minarr) {
    int dir = blockIdx.z >> 1, half = blockIdx.z & 1;
    int b = blockIdx.y;
    int i = blockIdx.x*256 + threadIdx.x;
    const float* src = samples + (size_t)dir*B*NS*3;
    const float* dst = samples + (size_t)(1-dir)*B*NS*3;
    const float* sp = src + ((size_t)b*NS + i)*3;
    float px = sp[0], py = sp[1], pz = sp[2];
    const float* dmesh = dst + (size_t)b*NS*3 + (size_t)half*1024*3;

    __shared__ float4 tile[1024];
    for (int k = threadIdx.x; k < 1024; k += 256) {
        const float* q = dmesh + (size_t)k*3;
        tile[k] = make_float4(q[0], q[1], q[2], 0.f);
    }
    __syncthreads();

    float mind = 3.402823466e38f;
    #pragma unroll 4
    for (int j = 0; j < 1024; ++j) {
        float4 t = tile[j];
        float dx = px - t.x, dy = py - t.y, dz = pz - t.z;
        float d = dx*dx + dy*dy + dz*dz;
        mind = fminf(mind, d);
    }
    atomicMin(minarr + (size_t)dir*B*NS + (size_t)b*NS + i, __float_as_uint(mind));
}

__global__ void k_cham_reduce(const unsigned int* __restrict__ minarr, int B,
                              double* acc) {
    int gid = blockIdx.x*256 + threadIdx.x;   // 2*B*NS exact
    float v = __uint_as_float(minarr[gid]);
    int dir = gid >= B*NS;                    // block-uniform (B*NS % 256 == 0)
    float s = blockReduceSum256(v);
    if (threadIdx.x == 0) atomicAdd(acc + dir, (double)s);
}

// fused edge / normal-consistency / laplacian, segmented by blockIdx
__global__ void k_mesh(const float* __restrict__ vp, const int* __restrict__ edges,
                       const int* __restrict__ ncp, int B, int E, int P,
                       int nbE, int nbP, double* acc) {
    int bx = blockIdx.x;
    float val = 0.f;
    int accIdx;
    if (bx < nbE) {
        accIdx = 2;
        int gid = bx*256 + threadIdx.x;
        if (gid < B*E) {
            int b = gid / E, e = gid - b*E;
            const float* verts = vp + (size_t)b*NV*3;
            int2 ed = ((const int2*)edges)[e];
            F3 d = f3sub(ldv3(verts, ed.x), ldv3(verts, ed.y));
            val = f3dot(d, d);
        }
    } else if (bx < nbE + nbP) {
        accIdx = 3;
        int gid = (bx - nbE)*256 + threadIdx.x;
        if (gid < B*P) {
            int b = gid / P, p = gid - b*P;
            const float* verts = vp + (size_t)b*NV*3;
            int4 q = ((const int4*)ncp)[p];
            F3 v0 = ldv3(verts, q.x), v1 = ldv3(verts, q.y);
            F3 a = ldv3(verts, q.z), bb = ldv3(verts, q.w);
            F3 e = f3sub(v1, v0);
            F3 n0 = f3cross(e, f3sub(a, v0));
            F3 n1 = f3cross(f3sub(bb, v0), e);   // == -cross(e, bb-v0)
            float num = f3dot(n0, n1);
            float den = fmaxf(sqrtf(f3dot(n0, n0)), 1e-8f) *
                        fmaxf(sqrtf(f3dot(n1, n1)), 1e-8f);
            val = 1.f - num / den;
        }
    } else {
        accIdx = 4;
        int gid = (bx - nbE - nbP)*256 + threadIdx.x;
        if (gid < B*NV) {
            int b = gid / NV, idx = gid - b*NV;
            int i = idx / GSZ, j = idx - i*GSZ;
            const float* verts = vp + (size_t)b*NV*3;
            F3 c = ldv3(verts, idx);
            float nx = 0.f, ny = 0.f, nz = 0.f; int deg = 0;
            #define ADDN(ii, jj) { F3 n_ = ldv3(verts, (ii)*GSZ + (jj)); \
                                   nx += n_.x; ny += n_.y; nz += n_.z; ++deg; }
            if (j > 0)               ADDN(i, j-1);
            if (j < GSZ-1)           ADDN(i, j+1);
            if (i > 0)               ADDN(i-1, j);
            if (i < GSZ-1)           ADDN(i+1, j);
            if (i < GSZ-1 && j > 0)  ADDN(i+1, j-1);   // anti-diagonal edges
            if (i > 0 && j < GSZ-1)  ADDN(i-1, j+1);
            #undef ADDN
            float inv = 1.f / (float)deg;
            float lx = nx*inv - c.x, ly = ny*inv - c.y, lz = nz*inv - c.z;
            val = sqrtf(lx*lx + ly*ly + lz*lz);
        }
    }
    float s = blockReduceSum256(val);
    if (threadIdx.x == 0) atomicAdd(acc + accIdx, (double)s);
}

__global__ void k_final(const double* __restrict__ acc, int B, int E, int P,
                        float* __restrict__ out) {
    double bn = (double)B * NS;
    double ch = acc[0]/bn + acc[1]/bn;
    double ed = acc[2] / ((double)B * E);
    double no = acc[3] / ((double)B * P);
    double la = acc[4] / ((double)B * NV);
    double loss = ch + ed + 0.1*no + 0.1*la;
    out[0] = (float)loss; out[1] = (float)ch; out[2] = (float)ed;
    out[3] = (float)no;   out[4] = (float)la;
}

extern "C" void kernel_launch(void* const* d_in, const int* in_sizes, int n_in,
                              void* d_out, int out_size, void* d_ws, size_t ws_size,
                              hipStream_t stream) {
    const float* vp = (const float*)d_in[0];
    const float* vt = (const float*)d_in[1];
    const int* faces = (const int*)d_in[2];
    const int* edges = (const int*)d_in[3];
    const int* ncp   = (const int*)d_in[4];
    const int B = in_sizes[0] / (3*NV);
    const int F = in_sizes[2] / 3;
    const int E = in_sizes[3] / 2;
    const int P = in_sizes[4] / 4;

    char* ws = (char*)d_ws;
    double* acc = (double*)ws;                               // 5 doubles
    unsigned int* maxAreaU = (unsigned int*)(ws + 40);
    float* samples = (float*)(ws + 64);                      // 2*B*NS*3 floats
    unsigned int* minarr =
        (unsigned int*)(ws + 64 + (size_t)2*B*NS*3*sizeof(float)); // 2*B*NS uints

    int nMin = 2*B*NS;
    k_init<<<(nMin + 255)/256, 256, 0, stream>>>(acc, maxAreaU, minarr, nMin);
    k_maxarea<<<512, 256, 0, stream>>>(vp, vt, faces, B, F, maxAreaU);
    k_sample<<<(2*B*NS)/256, 256, 0, stream>>>(vp, vt, faces, B, F, maxAreaU, samples);
    dim3 gch(NS/256, B, 4);
    k_chamfer<<<gch, 256, 0, stream>>>(samples, B, minarr);
    k_cham_reduce<<<(2*B*NS)/256, 256, 0, stream>>>(minarr, B, acc);
    int nbE = (B*E + 255)/256, nbP = (B*P + 255)/256, nbV = (B*NV + 255)/256;
    k_mesh<<<nbE + nbP + nbV, 256, 0, stream>>>(vp, edges, ncp, B, E, P, nbE, nbP, acc);
    k_final<<<1, 1, 0, stream>>>(acc, B, E, P, (float*)d_out);
}

// Round 2
// 147.647 us; speedup vs baseline: 2.7756x; 2.7756x over previous
//
#include <hip/hip_runtime.h>
#include <stdint.h>

#define GSZ 256
#define NV (GSZ*GSZ)
#define NS 2048
#define CELLS (255*255)          // 65025 cells per mesh
#define FH CELLS                 // first-half face count
#define NF (2*CELLS)             // 130050 faces per mesh
#define CH 8                     // chunks per k_mesh block

struct F3 { float x, y, z; };

__device__ __forceinline__ F3 ldv3(const float* __restrict__ p, int idx) {
    const float* q = p + 3*(size_t)idx;
    F3 r; r.x = q[0]; r.y = q[1]; r.z = q[2]; return r;
}
__device__ __forceinline__ F3 f3sub(F3 a, F3 b) { return F3{a.x-b.x, a.y-b.y, a.z-b.z}; }
__device__ __forceinline__ F3 f3cross(F3 a, F3 b) {
    return F3{a.y*b.z - a.z*b.y, a.z*b.x - a.x*b.z, a.x*b.y - a.y*b.x};
}
__device__ __forceinline__ float f3dot(F3 a, F3 b) { return a.x*b.x + a.y*b.y + a.z*b.z; }

__device__ __forceinline__ uint64_t splitmix64(uint64_t& s) {
    s += 0x9E3779B97F4A7C15ULL;
    uint64_t z = s;
    z = (z ^ (z >> 30)) * 0xBF58476D1CE4E5B9ULL;
    z = (z ^ (z >> 27)) * 0x94D049BB133111EBULL;
    return z ^ (z >> 31);
}

// result valid on thread 0 only; blockDim.x == 256
__device__ __forceinline__ float blockReduceSum256(float v) {
    __shared__ float s[4];
    int lane = threadIdx.x & 63, w = threadIdx.x >> 6;
    #pragma unroll
    for (int o = 32; o > 0; o >>= 1) v += __shfl_down(v, o, 64);
    if (lane == 0) s[w] = v;
    __syncthreads();
    if (threadIdx.x == 0) v = s[0] + s[1] + s[2] + s[3];
    return v;
}

// ---------------------------------------------------------------------------
// k_area: vertex-centric area table. One thread per cell per mesh (both
// clouds). Coalesced row loads; analytic grid topology; writes areas + block
// max (no atomics, no init needed).
// grid: ceil(2*B*CELLS/256) blocks
__global__ void k_area(const float* __restrict__ vp, const float* __restrict__ vt,
                       int B, float* __restrict__ areas, float* __restrict__ blockmax) {
    int gid = blockIdx.x*256 + threadIdx.x;
    int total = 2*B*CELLS;
    float mloc = 0.f;
    if (gid < total) {
        int m = gid / CELLS;              // mesh id (0..2B)
        int c = gid - m*CELLS;            // cell id
        int i = c / 255, j = c - i*255;
        const float* verts = (m < B ? vp + (size_t)m*NV*3
                                    : vt + (size_t)(m-B)*NV*3);
        int b00 = i*GSZ + j;
        F3 v00 = ldv3(verts, b00);
        F3 v01 = ldv3(verts, b00+1);
        F3 v10 = ldv3(verts, b00+GSZ);
        F3 v11 = ldv3(verts, b00+GSZ+1);
        F3 c1 = f3cross(f3sub(v01, v00), f3sub(v10, v00));
        F3 c2 = f3cross(f3sub(v11, v01), f3sub(v10, v01));
        float a1 = 0.5f * sqrtf(f3dot(c1, c1));
        float a2 = 0.5f * sqrtf(f3dot(c2, c2));
        size_t base = (size_t)m*NF;
        areas[base + c]      = a1;   // face f1[c]
        areas[base + FH + c] = a2;   // face f2[c]
        mloc = fmaxf(a1, a2);
    }
    #pragma unroll
    for (int o = 32; o > 0; o >>= 1) mloc = fmaxf(mloc, __shfl_down(mloc, o, 64));
    __shared__ float s[4];
    int lane = threadIdx.x & 63, w = threadIdx.x >> 6;
    if (lane == 0) s[w] = mloc;
    __syncthreads();
    if (threadIdx.x == 0)
        blockmax[blockIdx.x] = fmaxf(fmaxf(s[0], s[1]), fmaxf(s[2], s[3]));
}

// ---------------------------------------------------------------------------
// k_sample: area-weighted rejection sampling. Candidates batched 4/round so
// area loads are independent (latency-hidden). Face vertex indices computed
// analytically from grid topology (no faces[] gathers).
// grid: (2*B*NS)/256 = 128 blocks
__global__ void k_sample(const float* __restrict__ vp, const float* __restrict__ vt,
                         int B, const float* __restrict__ areas,
                         const float* __restrict__ blockmax, int nbm,
                         float* __restrict__ samples) {
    // block-wide reduce of global max area
    float m = 0.f;
    for (int k = threadIdx.x; k < nbm; k += 256) m = fmaxf(m, blockmax[k]);
    #pragma unroll
    for (int o = 32; o > 0; o >>= 1) m = fmaxf(m, __shfl_down(m, o, 64));
    __shared__ float s[4];
    int lane = threadIdx.x & 63, w = threadIdx.x >> 6;
    if (lane == 0) s[w] = m;
    __syncthreads();
    __shared__ float sMaxA;
    if (threadIdx.x == 0) sMaxA = fmaxf(fmaxf(s[0], s[1]), fmaxf(s[2], s[3]));
    __syncthreads();
    float maxA = sMaxA;

    int gid = blockIdx.x*256 + threadIdx.x;       // 0 .. 2*B*NS
    int cloud = gid / (B*NS);
    int rem = gid - cloud*(B*NS);
    int b = rem / NS;
    const float* verts = (cloud ? vt : vp) + (size_t)b*NV*3;
    const float* am = areas + (size_t)(cloud*B + b)*NF;

    uint64_t st = ((uint64_t)(gid + 1) * 0x9E3779B97F4A7C15ULL) ^ 0xC0FFEE123456789ULL;
    int f = 0;
    for (int round = 0; round < 64; ++round) {
        uint64_t r0 = splitmix64(st), r1 = splitmix64(st);
        uint64_t r2 = splitmix64(st), r3 = splitmix64(st);
        int f0 = (int)(((uint64_t)(uint32_t)r0 * (uint32_t)NF) >> 32);
        int f1 = (int)(((uint64_t)(uint32_t)r1 * (uint32_t)NF) >> 32);
        int f2 = (int)(((uint64_t)(uint32_t)r2 * (uint32_t)NF) >> 32);
        int f3 = (int)(((uint64_t)(uint32_t)r3 * (uint32_t)NF) >> 32);
        float a0 = am[f0], a1 = am[f1], a2 = am[f2], a3 = am[f3];
        float u0 = ((uint32_t)(r0 >> 40)) * (1.f/16777216.f);
        float u1 = ((uint32_t)(r1 >> 40)) * (1.f/16777216.f);
        float u2 = ((uint32_t)(r2 >> 40)) * (1.f/16777216.f);
        float u3 = ((uint32_t)(r3 >> 40)) * (1.f/16777216.f);
        if (u0 * maxA <= a0) { f = f0; break; }
        if (u1 * maxA <= a1) { f = f1; break; }
        if (u2 * maxA <= a2) { f = f2; break; }
        if (u3 * maxA <= a3) { f = f3; break; }
        f = f3;   // fallback (practically unreachable)
    }
    // analytic face -> vertex indices (matches _grid_faces order)
    int i0, i1, i2;
    if (f < FH) {
        int c = f;  int i = c / 255, j = c - i*255;  int v = i*GSZ + j;
        i0 = v; i1 = v + 1; i2 = v + GSZ;                    // (v00, v01, v10)
    } else {
        int c = f - FH;  int i = c / 255, j = c - i*255;  int v = i*GSZ + j;
        i0 = v + 1; i1 = v + GSZ + 1; i2 = v + GSZ;          // (v01, v11, v10)
    }
    F3 v0 = ldv3(verts, i0), v1 = ldv3(verts, i1), v2 = ldv3(verts, i2);
    uint64_t r = splitmix64(st);
    float u0 = ((uint32_t)r >> 8) * (1.f/16777216.f);
    float u1 = ((uint32_t)(r >> 32) >> 8) * (1.f/16777216.f);
    float su = sqrtf(u0);
    float w0 = 1.f - su, w1 = su * (1.f - u1), w2 = su * u1;
    float* o = samples + (size_t)gid*3;
    o[0] = w0*v0.x + w1*v1.x + w2*v2.x;
    o[1] = w0*v0.y + w1*v1.y + w2*v2.y;
    o[2] = w0*v0.z + w1*v1.z + w2*v2.z;
}

// ---------------------------------------------------------------------------
// k_chamfer: 4 src points/thread (register tile), 128-pt dst tile in LDS.
// grid: (2 srcHalf, B, 32 = dir*16 + dstChunk) = 512 blocks. No atomics:
// each block writes its partial mins to a private slice.
__global__ void k_chamfer(const float* __restrict__ samples, int B,
                          float* __restrict__ minpart) {
    int dir = blockIdx.z >> 4, q = blockIdx.z & 15;
    int b = blockIdx.y, xh = blockIdx.x;
    const float* src = samples + ((size_t)dir*B + b)*NS*3;
    const float* dst = samples + ((size_t)(1-dir)*B + b)*NS*3;

    __shared__ float4 tile[128];
    if (threadIdx.x < 128) {
        const float* p = dst + (size_t)(q*128 + threadIdx.x)*3;
        tile[threadIdx.x] = make_float4(p[0], p[1], p[2], 0.f);
    }
    float px[4], py[4], pz[4], mn[4];
    #pragma unroll
    for (int k = 0; k < 4; ++k) {
        int i = xh*1024 + k*256 + threadIdx.x;
        const float* p = src + (size_t)i*3;
        px[k] = p[0]; py[k] = p[1]; pz[k] = p[2];
        mn[k] = 3.402823466e38f;
    }
    __syncthreads();
    #pragma unroll 2
    for (int j = 0; j < 128; ++j) {
        float4 t = tile[j];
        #pragma unroll
        for (int k = 0; k < 4; ++k) {
            float dx = px[k]-t.x, dy = py[k]-t.y, dz = pz[k]-t.z;
            mn[k] = fminf(mn[k], dx*dx + dy*dy + dz*dz);
        }
    }
    float* outp = minpart + (((size_t)(dir*B + b)*16) + q)*NS;
    #pragma unroll
    for (int k = 0; k < 4; ++k)
        outp[xh*1024 + k*256 + threadIdx.x] = mn[k];
}

// combine 16 dst-chunk partial mins per src point; block partial sums
// grid: (2*B*NS)/256 = 128 blocks
__global__ void k_cham_reduce(const float* __restrict__ minpart, int B,
                              float* __restrict__ chamPart) {
    int gid = blockIdx.x*256 + threadIdx.x;
    int dir = gid / (B*NS);
    int rem = gid - dir*(B*NS);
    int b = rem / NS, i = rem - b*NS;
    const float* p = minpart + (size_t)(dir*B + b)*16*NS + i;
    float mn = 3.402823466e38f;
    #pragma unroll
    for (int q = 0; q < 16; ++q) mn = fminf(mn, p[(size_t)q*NS]);
    float sm = blockReduceSum256(mn);
    if (threadIdx.x == 0) chamPart[blockIdx.x] = sm;   // blocks 0..63 dir0, 64..127 dir1
}

// ---------------------------------------------------------------------------
// fused edge / normal / laplacian. grid: (nbE+nbP+nbV, B). Each block handles
// CH=8 chunks of 256 elements of ONE mesh, ONE category; writes one partial.
__global__ void k_mesh(const float* __restrict__ vp, const int* __restrict__ edges,
                       const int* __restrict__ ncp, int B, int E, int P,
                       int nbE, int nbP,
                       float* __restrict__ partE, float* __restrict__ partP,
                       float* __restrict__ partV) {
    int bx = blockIdx.x, b = blockIdx.y;
    const float* verts = vp + (size_t)b*NV*3;
    float acc = 0.f;
    if (bx < nbE) {
        int base = bx*(256*CH);
        #pragma unroll 2
        for (int c = 0; c < CH; ++c) {
            int e = base + c*256 + threadIdx.x;
            if (e < E) {
                int2 ed = ((const int2*)edges)[e];
                F3 d = f3sub(ldv3(verts, ed.x), ldv3(verts, ed.y));
                acc += f3dot(d, d);
            }
        }
        float s = blockReduceSum256(acc);
        if (threadIdx.x == 0) partE[(size_t)bx*B + b] = s;
    } else if (bx < nbE + nbP) {
        int base = (bx - nbE)*(256*CH);
        for (int c = 0; c < CH; ++c) {
            int p = base + c*256 + threadIdx.x;
            if (p < P) {
                int4 q = ((const int4*)ncp)[p];
                F3 v0 = ldv3(verts, q.x), v1 = ldv3(verts, q.y);
                F3 a = ldv3(verts, q.z), bb = ldv3(verts, q.w);
                F3 e = f3sub(v1, v0);
                F3 n0 = f3cross(e, f3sub(a, v0));
                F3 n1 = f3cross(f3sub(bb, v0), e);     // == -cross(e, bb-v0)
                float num = f3dot(n0, n1);
                float den = fmaxf(sqrtf(f3dot(n0, n0)), 1e-8f) *
                            fmaxf(sqrtf(f3dot(n1, n1)), 1e-8f);
                acc += 1.f - num / den;
            }
        }
        float s = blockReduceSum256(acc);
        if (threadIdx.x == 0) partP[(size_t)(bx - nbE)*B + b] = s;
    } else {
        int base = (bx - nbE - nbP)*(256*CH);
        for (int c = 0; c < CH; ++c) {
            int idx = base + c*256 + threadIdx.x;      // < NV always (nbV exact)
            int i = idx >> 8, j = idx & 255;
            F3 ctr = ldv3(verts, idx);
            float nx = 0.f, ny = 0.f, nz = 0.f; int deg = 0;
            #define ADDN(ii, jj) { F3 n_ = ldv3(verts, (ii)*GSZ + (jj)); \
                                   nx += n_.x; ny += n_.y; nz += n_.z; ++deg; }
            if (j > 0)               ADDN(i, j-1);
            if (j < GSZ-1)           ADDN(i, j+1);
            if (i > 0)               ADDN(i-1, j);
            if (i < GSZ-1)           ADDN(i+1, j);
            if (i < GSZ-1 && j > 0)  ADDN(i+1, j-1);   // anti-diagonal
            if (i > 0 && j < GSZ-1)  ADDN(i-1, j+1);
            #undef ADDN
            float inv = 1.f / (float)deg;
            float lx = nx*inv - ctr.x, ly = ny*inv - ctr.y, lz = nz*inv - ctr.z;
            acc += sqrtf(lx*lx + ly*ly + lz*lz);
        }
        float s = blockReduceSum256(acc);
        if (threadIdx.x == 0) partV[(size_t)(bx - nbE - nbP)*B + b] = s;
    }
}

// ---------------------------------------------------------------------------
// final fp64 accumulation of all partial arrays; single block of 256 threads
__global__ void k_final(const float* __restrict__ chamPart,
                        const float* __restrict__ partE, int nE,
                        const float* __restrict__ partP, int nP,
                        const float* __restrict__ partV, int nL,
                        int B, int E, int P, float* __restrict__ out) {
    double a0 = 0, a1 = 0, aE = 0, aP = 0, aL = 0;
    for (int k = threadIdx.x; k < 64;  k += 256) a0 += (double)chamPart[k];
    for (int k = 64 + threadIdx.x; k < 128; k += 256) a1 += (double)chamPart[k];
    for (int k = threadIdx.x; k < nE; k += 256) aE += (double)partE[k];
    for (int k = threadIdx.x; k < nP; k += 256) aP += (double)partP[k];
    for (int k = threadIdx.x; k < nL; k += 256) aL += (double)partV[k];
    __shared__ double sd[5][4];
    double v[5] = {a0, a1, aE, aP, aL};
    int lane = threadIdx.x & 63, w = threadIdx.x >> 6;
    #pragma unroll
    for (int r = 0; r < 5; ++r) {
        double x = v[r];
        #pragma unroll
        for (int o = 32; o > 0; o >>= 1) x += __shfl_down(x, o, 64);
        if (lane == 0) sd[r][w] = x;
    }
    __syncthreads();
    if (threadIdx.x == 0) {
        double bn = (double)B * NS;
        double ch = (sd[0][0]+sd[0][1]+sd[0][2]+sd[0][3]) / bn
                  + (sd[1][0]+sd[1][1]+sd[1][2]+sd[1][3]) / bn;
        double ed = (sd[2][0]+sd[2][1]+sd[2][2]+sd[2][3]) / ((double)B * E);
        double no = (sd[3][0]+sd[3][1]+sd[3][2]+sd[3][3]) / ((double)B * P);
        double la = (sd[4][0]+sd[4][1]+sd[4][2]+sd[4][3]) / ((double)B * NV);
        double loss = ch + ed + 0.1*no + 0.1*la;
        out[0] = (float)loss; out[1] = (float)ch; out[2] = (float)ed;
        out[3] = (float)no;   out[4] = (float)la;
    }
}

extern "C" void kernel_launch(void* const* d_in, const int* in_sizes, int n_in,
                              void* d_out, int out_size, void* d_ws, size_t ws_size,
                              hipStream_t stream) {
    const float* vp = (const float*)d_in[0];
    const float* vt = (const float*)d_in[1];
    const int* edges = (const int*)d_in[3];
    const int* ncp   = (const int*)d_in[4];
    const int B = in_sizes[0] / (3*NV);
    const int E = in_sizes[3] / 2;
    const int P = in_sizes[4] / 4;

    char* ws = (char*)d_ws;
    size_t off = 0;
    float* areas    = (float*)(ws + off); off += (size_t)2*B*NF*sizeof(float);     // 8.3 MB
    float* samples  = (float*)(ws + off); off += (size_t)2*B*NS*3*sizeof(float);   // 393 KB
    float* minpart  = (float*)(ws + off); off += (size_t)2*B*16*NS*sizeof(float);  // 2.1 MB
    float* blockmax = (float*)(ws + off); off += 8192*sizeof(float);
    float* chamPart = (float*)(ws + off); off += 256*sizeof(float);
    float* partE    = (float*)(ws + off); off += 2048*sizeof(float);
    float* partP    = (float*)(ws + off); off += 2048*sizeof(float);
    float* partV    = (float*)(ws + off); off += 1024*sizeof(float);

    int nbm = (2*B*CELLS + 255)/256;                    // k_area blocks (4065)
    k_area<<<nbm, 256, 0, stream>>>(vp, vt, B, areas, blockmax);
    k_sample<<<(2*B*NS)/256, 256, 0, stream>>>(vp, vt, B, areas, blockmax, nbm, samples);
    dim3 gch(2, B, 32);
    k_chamfer<<<gch, 256, 0, stream>>>(samples, B, minpart);
    k_cham_reduce<<<(2*B*NS)/256, 256, 0, stream>>>(minpart, B, chamPart);
    int nbE = (E + 256*CH - 1)/(256*CH);
    int nbP = (P + 256*CH - 1)/(256*CH);
    int nbV = NV/(256*CH);
    dim3 gm(nbE + nbP + nbV, B);
    k_mesh<<<gm, 256, 0, stream>>>(vp, edges, ncp, B, E, P, nbE, nbP,
                                   partE, partP, partV);
    k_final<<<1, 256, 0, stream>>>(chamPart, partE, nbE*B, partP, nbP*B,
                                   partV, nbV*B, B, E, P, (float*)d_out);
}